// Round 8
// baseline (8861.547 us; speedup 1.0000x reference)
//
#include <hip/hip_runtime.h>
#include <stdint.h>

typedef unsigned short u16;
typedef short short8 __attribute__((ext_vector_type(8)));
typedef short short4v __attribute__((ext_vector_type(4)));
typedef float float4v __attribute__((ext_vector_type(4)));
typedef uint32_t uint2v __attribute__((ext_vector_type(2)));

#define HW 4096
#define SCL 0.18033688011112042f   /* 0.125 * log2(e) */

// async global->LDS DMA: per-lane global addr, LDS dest = wave-uniform base + lane*16
#define GLOAD_LDS(g, l) __builtin_amdgcn_global_load_lds( \
    (const __attribute__((address_space(1))) void*)(g),   \
    (__attribute__((address_space(3))) void*)(l), 16, 0, 0)

static __device__ __forceinline__ u16 f2bf(float f) {
  union { float f; uint32_t u; } v; v.f = f;
  uint32_t r = v.u + 0x7fffu + ((v.u >> 16) & 1u);
  return (u16)(r >> 16);
}
// fast round (ties-away) — fine for p >= 0
static __device__ __forceinline__ uint32_t f2bf_u32(float f) {
  union { float f; uint32_t u; } v; v.f = f;
  return (v.u + 0x8000u) >> 16;
}

// ---- kernel 1: x [4,256,4096] f32 -> Xtp [4,66,66,256] bf16 (spatially padded; halo pre-zeroed)
__global__ __launch_bounds__(256) void k_xt(const float* __restrict__ x, u16* __restrict__ Xtp) {
  __shared__ float t[32][33];
  const int b = blockIdx.z, c0 = blockIdx.y * 32, p0 = blockIdx.x * 32;
  const int tid = threadIdx.x;
  const int l8 = tid >> 5, lp = tid & 31;
#pragma unroll
  for (int i = 0; i < 4; i++) {
    int c = l8 + i * 8;
    t[c][lp] = x[(size_t)(b * 256 + c0 + c) * HW + p0 + lp];
  }
  __syncthreads();
#pragma unroll
  for (int i = 0; i < 4; i++) {
    int p = l8 + i * 8;
    int pp = p0 + p;
    int y = pp >> 6, xx = pp & 63;
    Xtp[((size_t)(b * 66 + y + 1) * 66 + (xx + 1)) * 256 + c0 + lp] = f2bf(t[lp][p]);
  }
}

// ---- kernel 2: repack weights -> Wt [9][384][256] bf16 (ci contiguous), bcat[384] f32
__global__ __launch_bounds__(256) void k_wprep(const float* __restrict__ qw, const float* __restrict__ qb,
    const float* __restrict__ kw, const float* __restrict__ kb,
    const float* __restrict__ vw, const float* __restrict__ vb,
    u16* __restrict__ Wt, float* __restrict__ bcat) {
  int tid = blockIdx.x * 256 + threadIdx.x;
  if (tid < 9 * 384 * 256) {
    int ci = tid & 255;
    int n = (tid >> 8) % 384;
    int off = tid / (384 * 256);
    float val;
    if (n < 64)       val = qw[(size_t)n * 2304 + ci * 9 + off];
    else if (n < 128) val = kw[(size_t)(n - 64) * 2304 + ci * 9 + off];
    else              val = vw[(size_t)(n - 128) * 2304 + ci * 9 + off];
    Wt[tid] = f2bf(val);
  }
  if (tid < 384) bcat[tid] = (tid < 64) ? qb[tid] : (tid < 128) ? kb[tid - 64] : vb[tid - 128];
}

// ---- kernel 3: BARRIER-FREE fused QKV conv. 9 shifted GEMMs, 128 pos x 128
// outch per block, K = 9*256, BK=32. Fragments are loaded DIRECTLY from
// global (A: Xtp 9MB L3-resident; B: Wt 1.7MB L2-resident) into a register
// double-buffer: no LDS, no __syncthreads in the K-loop -> the compiler
// waits only on the previous iteration's 8 loads (vmcnt(8)), a full
// iteration of latency cover, and waves drift freely (no barrier drain,
// the R6/R7 conv bottleneck). __launch_bounds__(256,2): ~170 VGPR, no
// R5-style load serialization.
__global__ __launch_bounds__(256, 2) void k_conv(const u16* __restrict__ Xtp,
    const u16* __restrict__ Wt, const float* __restrict__ bcat,
    u16* __restrict__ Qt, u16* __restrict__ Kt, u16* __restrict__ Vcf) {
  const int tid = threadIdx.x;
  const int b = blockIdx.z, ntile = blockIdx.y;
  const int p0 = blockIdx.x * 128, n0 = ntile * 128;
  const int w = tid >> 6, lane = tid & 63, l16 = lane & 15, quad = lane >> 4;
  const int mw = (w & 1) * 64, nw = (w >> 1) * 64;

  // per-lane fragment base pointers: A[m=l16][k=quad*8+t], B[n=l16][k=quad*8+t]
  const u16* ap[4]; const u16* bp[4];
#pragma unroll
  for (int mt = 0; mt < 4; mt++) {
    const int pos = p0 + mw + mt * 16 + l16, py = pos >> 6, px = pos & 63;
    ap[mt] = Xtp + ((size_t)(b * 66 + py) * 66 + px) * 256 + quad * 8;
  }
#pragma unroll
  for (int nt = 0; nt < 4; nt++)
    bp[nt] = Wt + (size_t)(n0 + nw + nt * 16 + l16) * 256 + quad * 8;

  float4v acc[4][4];
  const float4v zz = {0.f, 0.f, 0.f, 0.f};
#pragma unroll
  for (int i = 0; i < 4; i++)
#pragma unroll
    for (int j = 0; j < 4; j++) acc[i][j] = zz;

  short8 af[2][4], bf[2][4];
  // prologue: load ks=0 (tap 0, cb 0) into slot 0
#pragma unroll
  for (int mt = 0; mt < 4; mt++) af[0][mt] = *(const short8*)ap[mt];
#pragma unroll
  for (int nt = 0; nt < 4; nt++) bf[0][nt] = *(const short8*)bp[nt];

  for (int ks = 0; ks < 72; ks++) {
    const int cur = ks & 1;
    if (ks + 1 < 72) {
      const int ksn = ks + 1, off = ksn >> 3, cb = ksn & 7;
      const int dy = (off * 11) >> 5, dx = off - dy * 3;   // off/3, off%3
      const int ash = (dy * 66 + dx) * 256 + cb * 32;
      const size_t bsh = (size_t)off * 98304 + cb * 32;
#pragma unroll
      for (int mt = 0; mt < 4; mt++) af[cur ^ 1][mt] = *(const short8*)(ap[mt] + ash);
#pragma unroll
      for (int nt = 0; nt < 4; nt++) bf[cur ^ 1][nt] = *(const short8*)(bp[nt] + bsh);
    }
    if (ntile == 0) {
#pragma unroll
      for (int mt = 0; mt < 4; mt++)
#pragma unroll
        for (int nt = 0; nt < 4; nt++)
          acc[mt][nt] = __builtin_amdgcn_mfma_f32_16x16x32_bf16(bf[cur][nt], af[cur][mt], acc[mt][nt], 0, 0, 0);
    } else {
#pragma unroll
      for (int mt = 0; mt < 4; mt++)
#pragma unroll
        for (int nt = 0; nt < 4; nt++)
          acc[mt][nt] = __builtin_amdgcn_mfma_f32_16x16x32_bf16(af[cur][mt], bf[cur][nt], acc[mt][nt], 0, 0, 0);
    }
  }

  if (ntile == 0) {
    // D rows = out-channel, cols = pos -> lane writes 4 consecutive channels (8B)
#pragma unroll
    for (int mt = 0; mt < 4; mt++) {
      const int p = p0 + mw + mt * 16 + l16;
#pragma unroll
      for (int nt = 0; nt < 4; nt++) {
        const int nb = nw + nt * 16 + quad * 4;
        short4v o;
#pragma unroll
        for (int r = 0; r < 4; r++) o[r] = (short)f2bf(acc[mt][nt][r] + bcat[nb + r]);
        u16* dst = (nb < 64) ? (Qt + (size_t)(b * HW + p) * 64 + nb)
                             : (Kt + (size_t)(b * HW + p) * 64 + (nb - 64));
        *(short4v*)dst = o;
      }
    }
  } else {
    // D rows = pos, cols = channel -> lane writes 4 consecutive positions (8B) channel-first
#pragma unroll
    for (int mt = 0; mt < 4; mt++) {
      const int pb = p0 + mw + mt * 16 + quad * 4;
#pragma unroll
      for (int nt = 0; nt < 4; nt++) {
        const int c = (ntile - 1) * 128 + nw + nt * 16 + l16;
        const float bias = bcat[128 + c];
        short4v o;
#pragma unroll
        for (int r = 0; r < 4; r++) o[r] = (short)f2bf(acc[mt][nt][r] + bias);
        *(short4v*)(Vcf + (size_t)(b * 256 + c) * HW + pb) = o;
      }
    }
  }
}

// ---- kernel 4: flash attention (R6 structure — proven). Double-buffered LDS
// K/V staging via global_load_lds, ONE barrier per j-tile (DMA gets a full
// iteration to land before the drain). Grid (64 i-tiles, 4 b, 2 c-slices):
// block = 64 queries x 128 channels. XOR-swizzled unpadded LDS (2-way = free).
// Wave w owns q-rows i0..i0+15: QK^T (S^T layout), no-max exp softmax
// (scale-invariant after 1/l), P via per-wave LDS round-trip, PV -> O^T.
__global__ __launch_bounds__(256, 2) void k_attn(const u16* __restrict__ Qt,
    const u16* __restrict__ Kt, const u16* __restrict__ Vcf, float* __restrict__ out) {
  __shared__ __align__(16) u16 Kls[2][64 * 64];     // 16 KB  [row j][col d]  (swizzled)
  __shared__ __align__(16) u16 Vls[2][128 * 64];    // 32 KB  [row c][col j]  (swizzled)
  __shared__ __align__(16) u16 Pls[4][16][66];      // 8448 B per-wave P tile [i][j]
  const int tid = threadIdx.x;
  const int b = blockIdx.y, ib = blockIdx.x * 64, cs = blockIdx.z * 128;
  const int w = tid >> 6, lane = tid & 63, l16 = lane & 15, quad = lane >> 4;
  const int i0 = ib + w * 16;

  const u16* Kb = Kt + (size_t)b * HW * 64;
  const u16* Vb = Vcf + ((size_t)b * 256 + cs) * HW;

  // staging lane constants: lane covers (row lr, swizzled 16B-col (lane&7)^lr)
  const int lr = lane >> 3, lcx = (lane & 7) ^ lr;
  const size_t koff = (size_t)lr * 128 + (size_t)lcx * 16;        // K row = 128 B
  const size_t voff = (size_t)lr * (HW * 2) + (size_t)lcx * 16;   // V row = 8 KB

  // LDS read constants (u16 units): row*64 + swizzled col
  const int kA = (quad ^ (l16 & 7)) * 8;   // kk=0; kk=1 -> kA^32
  const int rowu = l16 * 64;

  // Q as B-operand: B[k=d=quad*8+t][n=i=l16]
  short8 qf[2];
  {
    const u16* qp = Qt + (size_t)(b * HW + i0 + l16) * 64 + quad * 8;
    qf[0] = *(const short8*)qp;
    qf[1] = *(const short8*)(qp + 32);
  }

  float4v of[8];
  const float4v zz = {0.f, 0.f, 0.f, 0.f};
#pragma unroll
  for (int nt = 0; nt < 8; nt++) of[nt] = zz;
  float lsum = 0.f;

  // ---- stage tile 0 into buffer 0 (wave w: K rows w*16.., V rows w*32..)
  {
    const char* kg = (const char*)Kb + (size_t)(w * 16) * 128;
    const char* vg = (const char*)Vb + (size_t)(w * 32) * (HW * 2);
#pragma unroll
    for (int g = 0; g < 2; g++)
      GLOAD_LDS(kg + g * 1024 + koff, &Kls[0][(w * 16 + g * 8) * 64]);
#pragma unroll
    for (int g = 0; g < 4; g++)
      GLOAD_LDS(vg + (size_t)g * 8 * (HW * 2) + voff, &Vls[0][(w * 32 + g * 8) * 64]);
  }
  __syncthreads();

  for (int jt = 0; jt < 64; jt++) {
    const int buf = jt & 1;
    // ---- stage next tile into buf^1 (DMA, overlaps this iteration's compute)
    {
      const int jn = ((jt + 1) & 63) * 64;
      const char* kg = (const char*)Kb + (size_t)(jn + w * 16) * 128;
      const char* vg = (const char*)Vb + (size_t)(w * 32) * (HW * 2) + (size_t)jn * 2;
#pragma unroll
      for (int g = 0; g < 2; g++)
        GLOAD_LDS(kg + g * 1024 + koff, &Kls[buf ^ 1][(w * 16 + g * 8) * 64]);
#pragma unroll
      for (int g = 0; g < 4; g++)
        GLOAD_LDS(vg + (size_t)g * 8 * (HW * 2) + voff, &Vls[buf ^ 1][(w * 32 + g * 8) * 64]);
    }

    // ---- S^T = (Q K^T)^T : lane holds S^T[j=nt*16+quad*4+r][i=l16]
    float4v sf[4];
#pragma unroll
    for (int nt = 0; nt < 4; nt++) sf[nt] = zz;
#pragma unroll
    for (int nt = 0; nt < 4; nt++) {
      short8 k0 = *(const short8*)&Kls[buf][nt * 1024 + rowu + kA];
      short8 k1 = *(const short8*)&Kls[buf][nt * 1024 + rowu + (kA ^ 32)];
      sf[nt] = __builtin_amdgcn_mfma_f32_16x16x32_bf16(k0, qf[0], sf[nt], 0, 0, 0);
      sf[nt] = __builtin_amdgcn_mfma_f32_16x16x32_bf16(k1, qf[1], sf[nt], 0, 0, 0);
    }

    // ---- P = exp2(S*SCL); pack pairs; 4x ds_write_b64; row sum
    float rs = 0.f;
#pragma unroll
    for (int nt = 0; nt < 4; nt++) {
      float p0 = exp2f(sf[nt][0] * SCL);
      float p1 = exp2f(sf[nt][1] * SCL);
      float p2 = exp2f(sf[nt][2] * SCL);
      float p3 = exp2f(sf[nt][3] * SCL);
      rs += (p0 + p1) + (p2 + p3);
      uint2v pd;
      pd[0] = f2bf_u32(p0) | (f2bf_u32(p1) << 16);
      pd[1] = f2bf_u32(p2) | (f2bf_u32(p3) << 16);
      *(uint2v*)&Pls[w][l16][nt * 16 + quad * 4] = pd;
    }
    rs += __shfl_xor(rs, 16);
    rs += __shfl_xor(rs, 32);
    lsum += rs;                    // lsum = l[i = i0 + l16], lane-aligned

    // pin LDS write->read order (same wave; DS in-order per wave)
    __builtin_amdgcn_sched_barrier(0);
    __builtin_amdgcn_s_waitcnt(0xC07F);   // lgkmcnt(0)
    __builtin_amdgcn_sched_barrier(0);

    // ---- O^T += V P : D[m=c=quad*4+r][n=i=l16], 8 channel-tiles of the slice
#pragma unroll
    for (int kk = 0; kk < 2; kk++) {
      short8 pfr = *(const short8*)&Pls[w][l16][kk * 32 + quad * 8];
      const int vcol = kk ? (kA ^ 32) : kA;
#pragma unroll
      for (int nt = 0; nt < 8; nt++) {
        short8 vf = *(const short8*)&Vls[buf][nt * 1024 + rowu + vcol];
        of[nt] = __builtin_amdgcn_mfma_f32_16x16x32_bf16(vf, pfr, of[nt], 0, 0, 0);
      }
    }
    __syncthreads();   // all waves done reading buf; next-tile DMA has landed
  }

  const float inv = 1.0f / lsum;
#pragma unroll
  for (int nt = 0; nt < 8; nt++)
#pragma unroll
    for (int r = 0; r < 4; r++)
      out[(size_t)(b * 256 + cs + nt * 16 + quad * 4 + r) * HW + i0 + l16] = of[nt][r] * inv;
}

extern "C" void kernel_launch(void* const* d_in, const int* in_sizes, int n_in,
                              void* d_out, int out_size, void* d_ws, size_t ws_size,
                              hipStream_t stream) {
  const float* x  = (const float*)d_in[0];
  const float* qw = (const float*)d_in[1];
  const float* qb = (const float*)d_in[2];
  const float* kw = (const float*)d_in[3];
  const float* kb = (const float*)d_in[4];
  const float* vw = (const float*)d_in[5];
  const float* vb = (const float*)d_in[6];
  float* out = (float*)d_out;
  char* ws = (char*)d_ws;
  u16*   Xtp = (u16*)(ws);
  u16*   Wt  = (u16*)(ws + 8921088);
  float* bc  = (float*)(ws + 10690560);
  u16*   Qt  = (u16*)(ws + 10692096);
  u16*   Kt  = (u16*)(ws + 12789248);
  u16*   Vcf = (u16*)(ws + 14886400);

  hipMemsetAsync(Xtp, 0, 8921088, stream);  // zero the spatial halo
  k_xt  <<<dim3(128, 8, 4), 256, 0, stream>>>(x, Xtp);
  k_wprep<<<3456, 256, 0, stream>>>(qw, qb, kw, kb, vw, vb, Wt, bc);
  k_conv<<<dim3(32, 3, 4), 256, 0, stream>>>(Xtp, Wt, bc, Qt, Kt, Vcf);
  k_attn<<<dim3(64, 4, 2), 256, 0, stream>>>(Qt, Kt, Vcf, out);
}

// Round 10
// 212.289 us; speedup vs baseline: 41.7428x; 41.7428x over previous
//
#include <hip/hip_runtime.h>
#include <stdint.h>

typedef unsigned short u16;
typedef short short8 __attribute__((ext_vector_type(8)));
typedef short short4v __attribute__((ext_vector_type(4)));
typedef float float4v __attribute__((ext_vector_type(4)));
typedef uint32_t uint2v __attribute__((ext_vector_type(2)));

#define HW 4096
#define SCL 0.18033688011112042f   /* 0.125 * log2(e) */

// async global->LDS DMA: per-lane global addr, LDS dest = wave-uniform base + lane*16
#define GLOAD_LDS(g, l) __builtin_amdgcn_global_load_lds( \
    (const __attribute__((address_space(1))) void*)(g),   \
    (__attribute__((address_space(3))) void*)(l), 16, 0, 0)

static __device__ __forceinline__ u16 f2bf(float f) {
  union { float f; uint32_t u; } v; v.f = f;
  uint32_t r = v.u + 0x7fffu + ((v.u >> 16) & 1u);
  return (u16)(r >> 16);
}
// fast round (ties-away) — fine for p >= 0
static __device__ __forceinline__ uint32_t f2bf_u32(float f) {
  union { float f; uint32_t u; } v; v.f = f;
  return (v.u + 0x8000u) >> 16;
}

// ---- kernel 1: x [4,256,4096] f32 -> Xtp [4,66,66,256] bf16 (spatially padded; halo pre-zeroed)
__global__ __launch_bounds__(256) void k_xt(const float* __restrict__ x, u16* __restrict__ Xtp) {
  __shared__ float t[32][33];
  const int b = blockIdx.z, c0 = blockIdx.y * 32, p0 = blockIdx.x * 32;
  const int tid = threadIdx.x;
  const int l8 = tid >> 5, lp = tid & 31;
#pragma unroll
  for (int i = 0; i < 4; i++) {
    int c = l8 + i * 8;
    t[c][lp] = x[(size_t)(b * 256 + c0 + c) * HW + p0 + lp];
  }
  __syncthreads();
#pragma unroll
  for (int i = 0; i < 4; i++) {
    int p = l8 + i * 8;
    int pp = p0 + p;
    int y = pp >> 6, xx = pp & 63;
    Xtp[((size_t)(b * 66 + y + 1) * 66 + (xx + 1)) * 256 + c0 + lp] = f2bf(t[lp][p]);
  }
}

// ---- kernel 2: repack weights -> Wt [9][384][256] bf16 (ci contiguous), bcat[384] f32
__global__ __launch_bounds__(256) void k_wprep(const float* __restrict__ qw, const float* __restrict__ qb,
    const float* __restrict__ kw, const float* __restrict__ kb,
    const float* __restrict__ vw, const float* __restrict__ vb,
    u16* __restrict__ Wt, float* __restrict__ bcat) {
  int tid = blockIdx.x * 256 + threadIdx.x;
  if (tid < 9 * 384 * 256) {
    int ci = tid & 255;
    int n = (tid >> 8) % 384;
    int off = tid / (384 * 256);
    float val;
    if (n < 64)       val = qw[(size_t)n * 2304 + ci * 9 + off];
    else if (n < 128) val = kw[(size_t)(n - 64) * 2304 + ci * 9 + off];
    else              val = vw[(size_t)(n - 128) * 2304 + ci * 9 + off];
    Wt[tid] = f2bf(val);
  }
  if (tid < 384) bcat[tid] = (tid < 64) ? qb[tid] : (tid < 128) ? kb[tid - 64] : vb[tid - 128];
}

// ---- kernel 3: fused QKV conv, DMA-staged LDS double-buffer (the R7-proven
// structure), retuned: 128 pos x 64 ch tiles -> grid 768 = 3 blocks/CU
// (co-resident waves hide the barrier drain; old grid was 1.5/CU), BK=64 ->
// 36 iterations (half the barriers, 2x latency cover per DMA). One barrier
// per iter: stage(next->buf^1) -> compute(buf) -> sync. LDS 48 KB/block,
// unpadded, 16B-chunk XOR swizzle (chunk ^ row&7) applied on the GLOBAL
// address side -> all ds_read_b128 2-way (free). ct<2 (Q,K tiles) use
// swapped-operand MFMA -> channel-last stores; ct>=2 (V) channel-first.
__global__ __launch_bounds__(256) void k_conv(const u16* __restrict__ Xtp,
    const u16* __restrict__ Wt, const float* __restrict__ bcat,
    u16* __restrict__ Qt, u16* __restrict__ Kt, u16* __restrict__ Vcf) {
  __shared__ __align__(16) u16 Als[2][128 * 64];   // 16 KB per buf [row pos][64 k]
  __shared__ __align__(16) u16 Bls[2][64 * 64];    // 8 KB per buf  [row ch ][64 k]
  const int tid = threadIdx.x;
  const int b = blockIdx.z, ct = blockIdx.y;       // ct: 0=Q, 1=K, 2..5=V slices
  const int p0 = blockIdx.x * 128, n0 = ct * 64;
  const int w = tid >> 6, lane = tid & 63, l16 = lane & 15, quad = lane >> 4;

  // DMA lane constants: 8 rows x 8 chunks(16B) per wave-DMA; global chunk = lc^lr
  const int lr = lane >> 3, lcx = (lane & 7) ^ lr;
  // A: 4 DMAs/wave, rows w*32 + g*8 + lr (pos rows)
  const u16* ag[4];
#pragma unroll
  for (int g = 0; g < 4; g++) {
    const int pos = p0 + w * 32 + g * 8 + lr;
    const int py = pos >> 6, px = pos & 63;
    ag[g] = Xtp + ((size_t)(b * 66 + py) * 66 + px) * 256 + lcx * 8;
  }
  // B: 2 DMAs/wave, rows w*16 + g*8 + lr (channel rows)
  const u16* bg[2];
#pragma unroll
  for (int g = 0; g < 2; g++)
    bg[g] = Wt + (size_t)(n0 + w * 16 + g * 8 + lr) * 256 + lcx * 8;

  // fragment LDS offsets (u16): row*64 + ((kchunk ^ (row&7)) * 8)
  const int rx = l16 & 7;

  float4v acc[2][4];
  const float4v zz = {0.f, 0.f, 0.f, 0.f};
#pragma unroll
  for (int i = 0; i < 2; i++)
#pragma unroll
    for (int j = 0; j < 4; j++) acc[i][j] = zz;

  // prologue: ks=0 (tap 0, cgroup 0) -> buf 0
#pragma unroll
  for (int g = 0; g < 4; g++) GLOAD_LDS(ag[g], &Als[0][(w * 32 + g * 8) * 64]);
#pragma unroll
  for (int g = 0; g < 2; g++) GLOAD_LDS(bg[g], &Bls[0][(w * 16 + g * 8) * 64]);
  __syncthreads();

  for (int ks = 0; ks < 36; ks++) {
    const int buf = ks & 1;
    if (ks + 1 < 36) {
      const int ksn = ks + 1, tap = ksn >> 2, cg = (ksn & 3) * 64;
      const int dy = (tap * 11) >> 5, dx = tap - dy * 3;   // tap/3, tap%3
      const int aoff = (dy * 66 + dx) * 256 + cg;
      const size_t boff = (size_t)tap * 98304 + cg;
#pragma unroll
      for (int g = 0; g < 4; g++) GLOAD_LDS(ag[g] + aoff, &Als[buf ^ 1][(w * 32 + g * 8) * 64]);
#pragma unroll
      for (int g = 0; g < 2; g++) GLOAD_LDS(bg[g] + boff, &Bls[buf ^ 1][(w * 16 + g * 8) * 64]);
    }

    short8 af[2][2], bfv[4][2];
#pragma unroll
    for (int mt = 0; mt < 2; mt++)
#pragma unroll
      for (int kk = 0; kk < 2; kk++)
        af[mt][kk] = *(const short8*)&Als[buf][(w * 32 + mt * 16 + l16) * 64 + (((kk * 4 + quad) ^ rx) * 8)];
#pragma unroll
    for (int nt = 0; nt < 4; nt++)
#pragma unroll
      for (int kk = 0; kk < 2; kk++)
        bfv[nt][kk] = *(const short8*)&Bls[buf][(nt * 16 + l16) * 64 + (((kk * 4 + quad) ^ rx) * 8)];

    if (ct < 2) {
#pragma unroll
      for (int mt = 0; mt < 2; mt++)
#pragma unroll
        for (int nt = 0; nt < 4; nt++)
#pragma unroll
          for (int kk = 0; kk < 2; kk++)
            acc[mt][nt] = __builtin_amdgcn_mfma_f32_16x16x32_bf16(bfv[nt][kk], af[mt][kk], acc[mt][nt], 0, 0, 0);
    } else {
#pragma unroll
      for (int mt = 0; mt < 2; mt++)
#pragma unroll
        for (int nt = 0; nt < 4; nt++)
#pragma unroll
          for (int kk = 0; kk < 2; kk++)
            acc[mt][nt] = __builtin_amdgcn_mfma_f32_16x16x32_bf16(af[mt][kk], bfv[nt][kk], acc[mt][nt], 0, 0, 0);
    }
    __syncthreads();
  }

  if (ct < 2) {
    // D rows = channel, cols = pos -> lane writes 4 consecutive channels (8B), channel-last
    u16* base = (ct == 0) ? Qt : Kt;
#pragma unroll
    for (int mt = 0; mt < 2; mt++) {
      const int p = p0 + w * 32 + mt * 16 + l16;
#pragma unroll
      for (int nt = 0; nt < 4; nt++) {
        const int nb = nt * 16 + quad * 4;
        short4v o;
#pragma unroll
        for (int r = 0; r < 4; r++) o[r] = (short)f2bf(acc[mt][nt][r] + bcat[ct * 64 + nb + r]);
        *(short4v*)(base + (size_t)(b * HW + p) * 64 + nb) = o;
      }
    }
  } else {
    // D rows = pos, cols = channel -> lane writes 4 consecutive positions (8B), channel-first
#pragma unroll
    for (int mt = 0; mt < 2; mt++) {
      const int pb = p0 + w * 32 + mt * 16 + quad * 4;
#pragma unroll
      for (int nt = 0; nt < 4; nt++) {
        const int cl = nt * 16 + l16;
        const int gc = (ct - 2) * 64 + cl;
        const float bias = bcat[ct * 64 + cl];
        short4v o;
#pragma unroll
        for (int r = 0; r < 4; r++) o[r] = (short)f2bf(acc[mt][nt][r] + bias);
        *(short4v*)(Vcf + (size_t)(b * 256 + gc) * HW + pb) = o;
      }
    }
  }
}

// ---- kernel 4: flash attention (R6 structure — proven, unchanged). Double-
// buffered LDS K/V staging via global_load_lds, ONE barrier per j-tile.
// Grid (64 i-tiles, 4 b, 2 c-slices): block = 64 queries x 128 channels.
// XOR-swizzled unpadded LDS. Wave w owns q-rows i0..i0+15: QK^T (S^T layout),
// no-max exp softmax (scale-invariant after 1/l), P via per-wave LDS
// round-trip, PV -> O^T.
__global__ __launch_bounds__(256, 2) void k_attn(const u16* __restrict__ Qt,
    const u16* __restrict__ Kt, const u16* __restrict__ Vcf, float* __restrict__ out) {
  __shared__ __align__(16) u16 Kls[2][64 * 64];     // 16 KB  [row j][col d]  (swizzled)
  __shared__ __align__(16) u16 Vls[2][128 * 64];    // 32 KB  [row c][col j]  (swizzled)
  __shared__ __align__(16) u16 Pls[4][16][66];      // 8448 B per-wave P tile [i][j]
  const int tid = threadIdx.x;
  const int b = blockIdx.y, ib = blockIdx.x * 64, cs = blockIdx.z * 128;
  const int w = tid >> 6, lane = tid & 63, l16 = lane & 15, quad = lane >> 4;
  const int i0 = ib + w * 16;

  const u16* Kb = Kt + (size_t)b * HW * 64;
  const u16* Vb = Vcf + ((size_t)b * 256 + cs) * HW;

  // staging lane constants: lane covers (row lr, swizzled 16B-col (lane&7)^lr)
  const int lr = lane >> 3, lcx = (lane & 7) ^ lr;
  const size_t koff = (size_t)lr * 128 + (size_t)lcx * 16;        // K row = 128 B
  const size_t voff = (size_t)lr * (HW * 2) + (size_t)lcx * 16;   // V row = 8 KB

  // LDS read constants (u16 units): row*64 + swizzled col
  const int kA = (quad ^ (l16 & 7)) * 8;   // kk=0; kk=1 -> kA^32
  const int rowu = l16 * 64;

  // Q as B-operand: B[k=d=quad*8+t][n=i=l16]
  short8 qf[2];
  {
    const u16* qp = Qt + (size_t)(b * HW + i0 + l16) * 64 + quad * 8;
    qf[0] = *(const short8*)qp;
    qf[1] = *(const short8*)(qp + 32);
  }

  float4v of[8];
  const float4v zz = {0.f, 0.f, 0.f, 0.f};
#pragma unroll
  for (int nt = 0; nt < 8; nt++) of[nt] = zz;
  float lsum = 0.f;

  // ---- stage tile 0 into buffer 0 (wave w: K rows w*16.., V rows w*32..)
  {
    const char* kg = (const char*)Kb + (size_t)(w * 16) * 128;
    const char* vg = (const char*)Vb + (size_t)(w * 32) * (HW * 2);
#pragma unroll
    for (int g = 0; g < 2; g++)
      GLOAD_LDS(kg + g * 1024 + koff, &Kls[0][(w * 16 + g * 8) * 64]);
#pragma unroll
    for (int g = 0; g < 4; g++)
      GLOAD_LDS(vg + (size_t)g * 8 * (HW * 2) + voff, &Vls[0][(w * 32 + g * 8) * 64]);
  }
  __syncthreads();

  for (int jt = 0; jt < 64; jt++) {
    const int buf = jt & 1;
    // ---- stage next tile into buf^1 (DMA, overlaps this iteration's compute)
    {
      const int jn = ((jt + 1) & 63) * 64;
      const char* kg = (const char*)Kb + (size_t)(jn + w * 16) * 128;
      const char* vg = (const char*)Vb + (size_t)(w * 32) * (HW * 2) + (size_t)jn * 2;
#pragma unroll
      for (int g = 0; g < 2; g++)
        GLOAD_LDS(kg + g * 1024 + koff, &Kls[buf ^ 1][(w * 16 + g * 8) * 64]);
#pragma unroll
      for (int g = 0; g < 4; g++)
        GLOAD_LDS(vg + (size_t)g * 8 * (HW * 2) + voff, &Vls[buf ^ 1][(w * 32 + g * 8) * 64]);
    }

    // ---- S^T = (Q K^T)^T : lane holds S^T[j=nt*16+quad*4+r][i=l16]
    float4v sf[4];
#pragma unroll
    for (int nt = 0; nt < 4; nt++) sf[nt] = zz;
#pragma unroll
    for (int nt = 0; nt < 4; nt++) {
      short8 k0 = *(const short8*)&Kls[buf][nt * 1024 + rowu + kA];
      short8 k1 = *(const short8*)&Kls[buf][nt * 1024 + rowu + (kA ^ 32)];
      sf[nt] = __builtin_amdgcn_mfma_f32_16x16x32_bf16(k0, qf[0], sf[nt], 0, 0, 0);
      sf[nt] = __builtin_amdgcn_mfma_f32_16x16x32_bf16(k1, qf[1], sf[nt], 0, 0, 0);
    }

    // ---- P = exp2(S*SCL); pack pairs; 4x ds_write_b64; row sum
    float rs = 0.f;
#pragma unroll
    for (int nt = 0; nt < 4; nt++) {
      float p0 = exp2f(sf[nt][0] * SCL);
      float p1 = exp2f(sf[nt][1] * SCL);
      float p2 = exp2f(sf[nt][2] * SCL);
      float p3 = exp2f(sf[nt][3] * SCL);
      rs += (p0 + p1) + (p2 + p3);
      uint2v pd;
      pd[0] = f2bf_u32(p0) | (f2bf_u32(p1) << 16);
      pd[1] = f2bf_u32(p2) | (f2bf_u32(p3) << 16);
      *(uint2v*)&Pls[w][l16][nt * 16 + quad * 4] = pd;
    }
    rs += __shfl_xor(rs, 16);
    rs += __shfl_xor(rs, 32);
    lsum += rs;                    // lsum = l[i = i0 + l16], lane-aligned

    // pin LDS write->read order (same wave; DS in-order per wave)
    __builtin_amdgcn_sched_barrier(0);
    __builtin_amdgcn_s_waitcnt(0xC07F);   // lgkmcnt(0)
    __builtin_amdgcn_sched_barrier(0);

    // ---- O^T += V P : D[m=c=quad*4+r][n=i=l16], 8 channel-tiles of the slice
#pragma unroll
    for (int kk = 0; kk < 2; kk++) {
      short8 pfr = *(const short8*)&Pls[w][l16][kk * 32 + quad * 8];
      const int vcol = kk ? (kA ^ 32) : kA;
#pragma unroll
      for (int nt = 0; nt < 8; nt++) {
        short8 vf = *(const short8*)&Vls[buf][nt * 1024 + rowu + vcol];
        of[nt] = __builtin_amdgcn_mfma_f32_16x16x32_bf16(vf, pfr, of[nt], 0, 0, 0);
      }
    }
    __syncthreads();   // all waves done reading buf; next-tile DMA has landed
  }

  const float inv = 1.0f / lsum;
#pragma unroll
  for (int nt = 0; nt < 8; nt++)
#pragma unroll
    for (int r = 0; r < 4; r++)
      out[(size_t)(b * 256 + cs + nt * 16 + quad * 4 + r) * HW + i0 + l16] = of[nt][r] * inv;
}

extern "C" void kernel_launch(void* const* d_in, const int* in_sizes, int n_in,
                              void* d_out, int out_size, void* d_ws, size_t ws_size,
                              hipStream_t stream) {
  const float* x  = (const float*)d_in[0];
  const float* qw = (const float*)d_in[1];
  const float* qb = (const float*)d_in[2];
  const float* kw = (const float*)d_in[3];
  const float* kb = (const float*)d_in[4];
  const float* vw = (const float*)d_in[5];
  const float* vb = (const float*)d_in[6];
  float* out = (float*)d_out;
  char* ws = (char*)d_ws;
  u16*   Xtp = (u16*)(ws);
  u16*   Wt  = (u16*)(ws + 8921088);
  float* bc  = (float*)(ws + 10690560);
  u16*   Qt  = (u16*)(ws + 10692096);
  u16*   Kt  = (u16*)(ws + 12789248);
  u16*   Vcf = (u16*)(ws + 14886400);

  hipMemsetAsync(Xtp, 0, 8921088, stream);  // zero the spatial halo
  k_xt  <<<dim3(128, 8, 4), 256, 0, stream>>>(x, Xtp);
  k_wprep<<<3456, 256, 0, stream>>>(qw, qb, kw, kb, vw, vb, Wt, bc);
  k_conv<<<dim3(32, 6, 4), 256, 0, stream>>>(Xtp, Wt, bc, Qt, Kt, Vcf);
  k_attn<<<dim3(64, 4, 2), 256, 0, stream>>>(Qt, Kt, Vcf, out);
}